// Round 8
// baseline (24604.343 us; speedup 1.0000x reference)
//
#include <hip/hip_runtime.h>
#include <hip/hip_bf16.h>
#include <hip/hip_fp16.h>

#define Bb 256
#define Ll 1024
#define Ff 64
#define Ee 128
#define Hh 128

__device__ __forceinline__ float fast_tanh(float x) {
  float e = __expf(2.0f * x);
  return 1.0f - 2.0f / (e + 1.0f);
}
__device__ __forceinline__ float fast_sigmoid(float x) {
  return 1.0f / (1.0f + __expf(-x));
}
// sum over the 4 K-slice lanes {jj, jj+16, jj+32, jj+48}
__device__ __forceinline__ float redu4(float v) {
  v += __shfl_xor(v, 16);
  v += __shfl_xor(v, 32);
  return v;
}
// full 64-lane sum
__device__ __forceinline__ float redu64(float v) {
#pragma unroll
  for (int o = 1; o < 64; o <<= 1) v += __shfl_xor(v, o);
  return v;
}

// Fully fused: one WG per batch row, zero workspace. OUTPUT IS FLOAT32.
// launch_bounds(512,1): 1 block/CU, 2 waves/SIMD -> VGPR cap 256 (was 128 -> spills).
__global__ __launch_bounds__(512, 1) void k_fused(
    const float* __restrict__ x, const float* __restrict__ dtp,
    const int* __restrict__ mask,
    const float* __restrict__ Wx, const float* __restrict__ bx,
    const float* __restrict__ W1, const float* __restrict__ b1,
    const float* __restrict__ W2, const float* __restrict__ b2,
    const float* __restrict__ Wih, const float* __restrict__ bih,
    const float* __restrict__ Whh, const float* __restrict__ bhh,
    const float* __restrict__ lng, const float* __restrict__ lnb,
    const float* __restrict__ Whd, const float* __restrict__ bhp,
    float* __restrict__ out)
{
  const int b = blockIdx.x;
  const int tid = threadIdx.x;
  const int lane = tid & 63;
  const int wv = tid >> 6;
  const int jj = lane & 15;
  const int ks = lane >> 4;
  const int j = (wv << 4) + jj;     // 0..127
  const int k016 = ks << 4;         // 16-wide slice base (F=64)
  const int k032 = ks << 5;         // 32-wide slice base (K=128)

  __shared__ int   act_lds[Ll];     // 4 KB
  __shared__ __align__(16) float x_lds[Ff];
  __shared__ __align__(16) float xe_lds[Ee];
  __shared__ __align__(16) float gi_lds[3 * Hh];
  __shared__ __align__(16) float h_lds[Hh];
  __shared__ __align__(16) float u_lds[Hh];
  __shared__ float red_lds[8];

  // ---- phase 0: act[t] = any_b mask[b][t] (same result in every WG) ----
  for (int t = tid; t < Ll; t += 512) {
    int a = 0;
    for (int bb = 0; bb < Bb; ++bb) a |= mask[(size_t)bb * Ll + t];
    act_lds[t] = a;
  }

  // ---- weights to registers ----
  float wx[16];
#pragma unroll
  for (int c = 0; c < 16; ++c) wx[c] = Wx[(size_t)j * Ff + k016 + c];

  float w1r[32], w2r[32];
#pragma unroll
  for (int ii = 0; ii < 8; ++ii) {
    const int slot = (ii + 2 * ks) & 7;      // bank-staggered rotation
    const int kb = k032 + 4 * slot;
    float4 a4;
    a4 = *(const float4*)&W1[(size_t)j * Hh + kb];
    w1r[4*ii+0]=a4.x; w1r[4*ii+1]=a4.y; w1r[4*ii+2]=a4.z; w1r[4*ii+3]=a4.w;
    a4 = *(const float4*)&W2[(size_t)j * Hh + kb];
    w2r[4*ii+0]=a4.x; w2r[4*ii+1]=a4.y; w2r[4*ii+2]=a4.z; w2r[4*ii+3]=a4.w;
  }

  // W_ih, W_hh packed f16 (f32 accumulate at use)
  __half2 wih[3][16], whhp[3][16];
#pragma unroll
  for (int G = 0; G < 3; ++G) {
#pragma unroll
    for (int ii = 0; ii < 8; ++ii) {
      const int slot = (ii + 2 * ks) & 7;
      const int kb = k032 + 4 * slot;
      float4 a4;
      a4 = *(const float4*)&Wih[((size_t)(G * Hh + j)) * Ee + kb];
      wih[G][2*ii+0] = __halves2half2(__float2half_rn(a4.x), __float2half_rn(a4.y));
      wih[G][2*ii+1] = __halves2half2(__float2half_rn(a4.z), __float2half_rn(a4.w));
      a4 = *(const float4*)&Whh[((size_t)(G * Hh + j)) * Hh + kb];
      whhp[G][2*ii+0] = __halves2half2(__float2half_rn(a4.x), __float2half_rn(a4.y));
      whhp[G][2*ii+1] = __halves2half2(__float2half_rn(a4.z), __float2half_rn(a4.w));
    }
  }
  const float bxj = bx[j];
  const float b1j = b1[j], b2j = b2[j];
  const float bir = bih[j], biz = bih[Hh + j], bin_ = bih[2*Hh + j];
  const float bhr = bhh[j], bhz = bhh[Hh + j], bhn = bhh[2*Hh + j];

  // ---- LN/head constants: c1 = sum(g*wh), c0 = sum(b*wh) + bh ----
  float gw = 0.0f;
  {
    float t1 = 0.0f, t0 = 0.0f;
    if (tid < Hh) {
      const float g = lng[tid], bbv = lnb[tid], wh = Whd[tid];
      gw = g * wh;
      t1 = gw;
      t0 = bbv * wh;
    }
    t1 = redu64(t1); t0 = redu64(t0);
    if (tid < Hh && lane == 0) { red_lds[wv*2+0] = t1; red_lds[wv*2+1] = t0; }
    if (tid < Hh) h_lds[tid] = 0.0f;
  }
  __syncthreads();
  const float c1 = red_lds[0] + red_lds[2];
  const float c0 = red_lds[1] + red_lds[3] + bhp[0];

  float hreg = 0.0f;                 // ks==0 lanes: h[j]
  float acc = 0.0f, cnt = 0.0f;      // tid==0: masked logit sum / count

#pragma unroll 1
  for (int t = 0; t < Ll; ++t) {
    if (tid < 16)
      *(float4*)&x_lds[4*tid] = *(const float4*)(x + ((size_t)b * Ll + t) * Ff + 4*tid);
    const float dtv = dtp[(size_t)b * Ll + t];
    const int m = mask[(size_t)b * Ll + t];
    const int act = act_lds[t];
    const float stepv = dtv * (float)m * 0.25f;
    __syncthreads();                                 // (b) x ready

    // ---- xe = relu(x @ Wx^T + bx) ----
    float p = 0.0f;
#pragma unroll
    for (int c = 0; c < 16; ++c) p = fmaf(wx[c], x_lds[k016 + c], p);
    p = redu4(p);
    if (ks == 0) xe_lds[j] = fmaxf(p + bxj, 0.0f);
    __syncthreads();                                 // (c) xe ready

    // ---- gi = xe @ W_ih^T + b_ih (r,z,n) ----
    float gr = 0.0f, gz = 0.0f, gn = 0.0f;
#pragma unroll
    for (int ii = 0; ii < 8; ++ii) {
      const int slot = (ii + 2 * ks) & 7;
      const float4 ev = *(const float4*)&xe_lds[k032 + 4*slot];
      float2 lo, hi;
      lo = __half22float2(wih[0][2*ii]); hi = __half22float2(wih[0][2*ii+1]);
      gr = fmaf(lo.x, ev.x, gr); gr = fmaf(lo.y, ev.y, gr);
      gr = fmaf(hi.x, ev.z, gr); gr = fmaf(hi.y, ev.w, gr);
      lo = __half22float2(wih[1][2*ii]); hi = __half22float2(wih[1][2*ii+1]);
      gz = fmaf(lo.x, ev.x, gz); gz = fmaf(lo.y, ev.y, gz);
      gz = fmaf(hi.x, ev.z, gz); gz = fmaf(hi.y, ev.w, gz);
      lo = __half22float2(wih[2][2*ii]); hi = __half22float2(wih[2][2*ii+1]);
      gn = fmaf(lo.x, ev.x, gn); gn = fmaf(lo.y, ev.y, gn);
      gn = fmaf(hi.x, ev.z, gn); gn = fmaf(hi.y, ev.w, gn);
    }
    gr = redu4(gr); gz = redu4(gz); gn = redu4(gn);
    if (ks == 0) {
      gi_lds[j]        = gr + bir;
      gi_lds[Hh + j]   = gz + biz;
      gi_lds[2*Hh + j] = gn + bin_;
    }
    // no barrier: gi_lds first consumed after the ODE barriers below

    // ---- ODE: 4 Euler substeps ----
#pragma unroll 1
    for (int s = 0; s < 4; ++s) {
      float pa = 0.0f;
#pragma unroll
      for (int ii = 0; ii < 8; ++ii) {
        const int slot = (ii + 2 * ks) & 7;
        const float4 hv = *(const float4*)&h_lds[k032 + 4*slot];
        pa = fmaf(w1r[4*ii+0], hv.x, pa); pa = fmaf(w1r[4*ii+1], hv.y, pa);
        pa = fmaf(w1r[4*ii+2], hv.z, pa); pa = fmaf(w1r[4*ii+3], hv.w, pa);
      }
      pa = redu4(pa);
      if (ks == 0) u_lds[j] = fast_tanh(pa + b1j);
      __syncthreads();
      float qa = 0.0f;
#pragma unroll
      for (int ii = 0; ii < 8; ++ii) {
        const int slot = (ii + 2 * ks) & 7;
        const float4 uv = *(const float4*)&u_lds[k032 + 4*slot];
        qa = fmaf(w2r[4*ii+0], uv.x, qa); qa = fmaf(w2r[4*ii+1], uv.y, qa);
        qa = fmaf(w2r[4*ii+2], uv.z, qa); qa = fmaf(w2r[4*ii+3], uv.w, qa);
      }
      qa = redu4(qa);
      if (ks == 0) { hreg = fmaf(stepv, qa + b2j, hreg); h_lds[j] = hreg; }
      __syncthreads();
    }

    // ---- GRU gates: gh = h @ W_hh^T ----
    float pr = 0.0f, pz = 0.0f, pn = 0.0f;
#pragma unroll
    for (int ii = 0; ii < 8; ++ii) {
      const int slot = (ii + 2 * ks) & 7;
      const float4 hv = *(const float4*)&h_lds[k032 + 4*slot];
      float2 lo, hi;
      lo = __half22float2(whhp[0][2*ii]); hi = __half22float2(whhp[0][2*ii+1]);
      pr = fmaf(lo.x, hv.x, pr); pr = fmaf(lo.y, hv.y, pr);
      pr = fmaf(hi.x, hv.z, pr); pr = fmaf(hi.y, hv.w, pr);
      lo = __half22float2(whhp[1][2*ii]); hi = __half22float2(whhp[1][2*ii+1]);
      pz = fmaf(lo.x, hv.x, pz); pz = fmaf(lo.y, hv.y, pz);
      pz = fmaf(hi.x, hv.z, pz); pz = fmaf(hi.y, hv.w, pz);
      lo = __half22float2(whhp[2][2*ii]); hi = __half22float2(whhp[2][2*ii+1]);
      pn = fmaf(lo.x, hv.x, pn); pn = fmaf(lo.y, hv.y, pn);
      pn = fmaf(hi.x, hv.z, pn); pn = fmaf(hi.y, hv.w, pn);
    }
    pr = redu4(pr); pz = redu4(pz); pn = redu4(pn);
    __syncthreads();                                 // (e) all done reading h_lds

    if (ks == 0) {
      const float r = fast_sigmoid(gi_lds[j] + pr + bhr);
      const float z = fast_sigmoid(gi_lds[Hh + j] + pz + bhz);
      const float n = fast_tanh(gi_lds[2*Hh + j] + r * (pn + bhn));
      const float hg = (1.0f - z) * n + z * hreg;
      if (act) hreg = hg;                            // h_new = active ? hg : h
      h_lds[j] = hreg;
    }
    __syncthreads();                                 // (f) h_new visible

    // ---- LN + head contribution (inline) ----
    float s1 = 0.0f, s2 = 0.0f, sd = 0.0f;
    if (tid < Hh) {
      const float hv = h_lds[tid];
      s1 = hv; s2 = hv * hv; sd = hv * gw;
    }
    s1 = redu64(s1); s2 = redu64(s2); sd = redu64(sd);
    if (tid < Hh && lane == 0) {
      red_lds[wv*3+0] = s1; red_lds[wv*3+1] = s2; red_lds[wv*3+2] = sd;
    }
    __syncthreads();                                 // (g) partials visible
    if (tid == 0 && m) {
      const float S1 = red_lds[0] + red_lds[3];
      const float S2 = red_lds[1] + red_lds[4];
      const float SD = red_lds[2] + red_lds[5];
      const float mu = S1 * (1.0f / 128.0f);
      const float var = S2 * (1.0f / 128.0f) - mu * mu;
      const float rstd = rsqrtf(var + 1e-5f);
      acc += rstd * (SD - mu * c1) + c0;
      cnt += 1.0f;
    }
  }

  if (tid == 0) out[b] = acc / fmaxf(cnt, 1.0f);   // FLOAT32 output
}

// ---------------- host ----------------
extern "C" void kernel_launch(void* const* d_in, const int* in_sizes, int n_in,
                              void* d_out, int out_size, void* d_ws, size_t ws_size,
                              hipStream_t stream) {
  const float* x    = (const float*)d_in[0];
  const float* dt   = (const float*)d_in[1];
  const int*   mask = (const int*)d_in[2];
  const float* Wx   = (const float*)d_in[3];
  const float* bx   = (const float*)d_in[4];
  const float* W1   = (const float*)d_in[5];
  const float* b1   = (const float*)d_in[6];
  const float* W2   = (const float*)d_in[7];
  const float* b2   = (const float*)d_in[8];
  const float* Wih  = (const float*)d_in[9];
  const float* bih  = (const float*)d_in[10];
  const float* Whh  = (const float*)d_in[11];
  const float* bhh  = (const float*)d_in[12];
  const float* lng  = (const float*)d_in[13];
  const float* lnb  = (const float*)d_in[14];
  const float* Wh   = (const float*)d_in[15];
  const float* bh   = (const float*)d_in[16];
  float* out = (float*)d_out;   // reference output dtype is float32

  k_fused<<<dim3(Bb), dim3(512), 0, stream>>>(
      x, dt, mask, Wx, bx, W1, b1, W2, b2, Wih, bih, Whh, bhh,
      lng, lnb, Wh, bh, out);
}

// Round 9
// 6163.523 us; speedup vs baseline: 3.9919x; 3.9919x over previous
//
#include <hip/hip_runtime.h>

#define Bb 256
#define Ll 1024
#define Ff 64
#define Ee 128
#define Hh 128

typedef _Float16 h2v __attribute__((ext_vector_type(2)));

__device__ __forceinline__ unsigned pack_h2(float a, float b) {
  h2v v; v[0] = (_Float16)a; v[1] = (_Float16)b;
  return __builtin_bit_cast(unsigned, v);
}
__device__ __forceinline__ float dot2(unsigned w, unsigned x, float acc) {
#if defined(__has_builtin)
#if __has_builtin(__builtin_amdgcn_fdot2)
  return __builtin_amdgcn_fdot2(__builtin_bit_cast(h2v, w),
                                __builtin_bit_cast(h2v, x), acc, false);
#else
  h2v wv = __builtin_bit_cast(h2v, w), xv = __builtin_bit_cast(h2v, x);
  acc = fmaf((float)wv[0], (float)xv[0], acc);
  return fmaf((float)wv[1], (float)xv[1], acc);
#endif
#else
  h2v wv = __builtin_bit_cast(h2v, w), xv = __builtin_bit_cast(h2v, x);
  acc = fmaf((float)wv[0], (float)xv[0], acc);
  return fmaf((float)wv[1], (float)xv[1], acc);
#endif
}

__device__ __forceinline__ float fast_tanh(float x) {
  float e = __expf(2.0f * x);
  return 1.0f - 2.0f / (e + 1.0f);
}
__device__ __forceinline__ float fast_sigmoid(float x) {
  return 1.0f / (1.0f + __expf(-x));
}
// sum over the 2 K-slice lanes {l, l+32}
__device__ __forceinline__ float redu2(float v) {
  v += __shfl_xor(v, 32);
  return v;
}
// full 64-lane sum
__device__ __forceinline__ float redu64(float v) {
#pragma unroll
  for (int o = 1; o < 64; o <<= 1) v += __shfl_xor(v, o);
  return v;
}

// One WG (256 thr, 4 waves) per batch row; 1 block/CU, 1 wave/SIMD -> VGPR cap 512.
// Thread (j = wave*32 + (lane&31), ks = lane>>5) owns output row j, 64-wide K-slice.
// W1/W2/Wx register-stationary f32; Wih/Whh register-stationary f16-pairs (dot2).
__global__ __launch_bounds__(256, 1) void k_fused(
    const float* __restrict__ x, const float* __restrict__ dtp,
    const int* __restrict__ mask,
    const float* __restrict__ Wx, const float* __restrict__ bx,
    const float* __restrict__ W1, const float* __restrict__ b1,
    const float* __restrict__ W2, const float* __restrict__ b2,
    const float* __restrict__ Wih, const float* __restrict__ bih,
    const float* __restrict__ Whh, const float* __restrict__ bhh,
    const float* __restrict__ lng, const float* __restrict__ lnb,
    const float* __restrict__ Whd, const float* __restrict__ bhp,
    float* __restrict__ out)
{
  const int b = blockIdx.x;
  const int tid = threadIdx.x;
  const int lane = tid & 63;
  const int wv = tid >> 6;          // 0..3
  const int jl = lane & 31;
  const int ks = lane >> 5;         // 0..1
  const int j = (wv << 5) + jl;     // 0..127
  const int k0f = ks << 5;          // 32-wide slice base (F=64)
  const int k0 = ks << 6;           // 64-wide slice base (K=128)
  const int q0 = ks << 5;           // 32 f16-pairs slice base

  __shared__ int act_lds[Ll];                       // 4 KB
  __shared__ __align__(16) float x_lds[Ff];
  __shared__ __align__(16) float h_lds[Hh];
  __shared__ __align__(16) float u_lds[Hh];
  __shared__ __align__(16) unsigned xe16[Ee / 2];   // f16 pairs
  __shared__ __align__(16) unsigned h16[Hh / 2];    // f16 pairs
  __shared__ float red_lds[8];

  // ---- phase 0: act[t] = any_b mask[b][t] (same in every WG) ----
  for (int t = tid; t < Ll; t += 256) {
    int a = 0;
    for (int bb = 0; bb < Bb; ++bb) a |= mask[(size_t)bb * Ll + t];
    act_lds[t] = a;
  }

  // ---- weights to registers ----
  float wx[32];
#pragma unroll
  for (int ii = 0; ii < 8; ++ii)
    *(float4*)&wx[4 * ii] = *(const float4*)&Wx[(size_t)j * Ff + k0f + 4 * ii];

  float w1r[64], w2r[64];
#pragma unroll
  for (int ii = 0; ii < 16; ++ii) {
    *(float4*)&w1r[4 * ii] = *(const float4*)&W1[(size_t)j * Hh + k0 + 4 * ii];
    *(float4*)&w2r[4 * ii] = *(const float4*)&W2[(size_t)j * Hh + k0 + 4 * ii];
  }

  unsigned wihd[3][32], whhd[3][32];
#pragma unroll
  for (int G = 0; G < 3; ++G) {
#pragma unroll
    for (int ii = 0; ii < 16; ++ii) {
      float4 a4;
      a4 = *(const float4*)&Wih[((size_t)(G * Hh + j)) * Ee + k0 + 4 * ii];
      wihd[G][2 * ii + 0] = pack_h2(a4.x, a4.y);
      wihd[G][2 * ii + 1] = pack_h2(a4.z, a4.w);
      a4 = *(const float4*)&Whh[((size_t)(G * Hh + j)) * Hh + k0 + 4 * ii];
      whhd[G][2 * ii + 0] = pack_h2(a4.x, a4.y);
      whhd[G][2 * ii + 1] = pack_h2(a4.z, a4.w);
    }
  }
  const float bxj = bx[j];
  const float b1j = b1[j], b2j = b2[j];
  const float bir = bih[j], biz = bih[Hh + j], bin_ = bih[2 * Hh + j];
  const float bhr = bhh[j], bhz = bhh[Hh + j], bhn = bhh[2 * Hh + j];

  // ---- LN/head constants ----
  float gw = 0.0f;
  {
    float t1 = 0.0f, t0 = 0.0f;
    if (tid < Hh) {
      const float g = lng[tid], bbv = lnb[tid], wh = Whd[tid];
      gw = g * wh;
      t1 = gw;
      t0 = bbv * wh;
    }
    t1 = redu64(t1); t0 = redu64(t0);
    if (tid < Hh && lane == 0) { red_lds[wv * 2 + 0] = t1; red_lds[wv * 2 + 1] = t0; }
    if (tid < Hh) h_lds[tid] = 0.0f;
    if (tid < Hh / 2) h16[tid] = 0u;
  }
  __syncthreads();
  const float c1 = red_lds[0] + red_lds[2];
  const float c0 = red_lds[1] + red_lds[3] + bhp[0];

  float hreg = 0.0f;                 // ks==0 lanes: h[j]
  float gir = 0.0f, giz = 0.0f, gin = 0.0f;
  float acc = 0.0f, cnt = 0.0f;      // tid==0

#pragma unroll 1
  for (int t = 0; t < Ll; ++t) {
    if (tid < 16)
      *(float4*)&x_lds[4 * tid] = *(const float4*)(x + ((size_t)b * Ll + t) * Ff + 4 * tid);
    const float dtv = dtp[(size_t)b * Ll + t];
    const int m = mask[(size_t)b * Ll + t];
    const int act = act_lds[t];
    const float stepv = dtv * (float)m * 0.25f;
    __syncthreads();                                 // (b) x ready

    // ---- xe = relu(x @ Wx^T + bx), packed to f16 pairs ----
    float p = 0.0f;
#pragma unroll
    for (int c = 0; c < 32; ++c) p = fmaf(wx[c], x_lds[k0f + c], p);
    p = redu2(p);
    if (ks == 0) {
      const float xev = fmaxf(p + bxj, 0.0f);
      const float xpart = __shfl_xor(xev, 1);
      if ((jl & 1) == 0) xe16[j >> 1] = pack_h2(xev, xpart);
    }
    __syncthreads();                                 // (c) xe16 ready

    // ---- gi = xe @ W_ih^T + b_ih (dot2, kept in registers) ----
    {
      float gr = 0.0f, gz = 0.0f, gn = 0.0f;
#pragma unroll
      for (int q = 0; q < 32; ++q) {
        const unsigned xv = xe16[q0 + q];
        gr = dot2(wihd[0][q], xv, gr);
        gz = dot2(wihd[1][q], xv, gz);
        gn = dot2(wihd[2][q], xv, gn);
      }
      gr = redu2(gr); gz = redu2(gz); gn = redu2(gn);
      gir = gr + bir; giz = gz + biz; gin = gn + bin_;
    }

    // ---- ODE: 4 Euler substeps (f32 path) ----
#pragma unroll 1
    for (int s = 0; s < 4; ++s) {
      float pa = 0.0f;
#pragma unroll
      for (int ii = 0; ii < 16; ++ii) {
        const float4 hv = *(const float4*)&h_lds[k0 + 4 * ii];
        pa = fmaf(w1r[4*ii+0], hv.x, pa); pa = fmaf(w1r[4*ii+1], hv.y, pa);
        pa = fmaf(w1r[4*ii+2], hv.z, pa); pa = fmaf(w1r[4*ii+3], hv.w, pa);
      }
      pa = redu2(pa);
      if (ks == 0) u_lds[j] = fast_tanh(pa + b1j);
      __syncthreads();                               // u ready (also: all pa reads of h done)
      float qa = 0.0f;
#pragma unroll
      for (int ii = 0; ii < 16; ++ii) {
        const float4 uv = *(const float4*)&u_lds[k0 + 4 * ii];
        qa = fmaf(w2r[4*ii+0], uv.x, qa); qa = fmaf(w2r[4*ii+1], uv.y, qa);
        qa = fmaf(w2r[4*ii+2], uv.z, qa); qa = fmaf(w2r[4*ii+3], uv.w, qa);
      }
      qa = redu2(qa);
      if (ks == 0) {
        hreg = fmaf(stepv, qa + b2j, hreg);
        h_lds[j] = hreg;
        if (s == 3) {                                // pack h for the GRU dot2
          const float hpart = __shfl_xor(hreg, 1);
          if ((jl & 1) == 0) h16[j >> 1] = pack_h2(hreg, hpart);
        }
      }
      __syncthreads();                               // h (and h16 at s==3) visible
    }

    // ---- GRU gates: gh = h @ W_hh^T (dot2) ----
    float pr = 0.0f, pz = 0.0f, pn = 0.0f;
#pragma unroll
    for (int q = 0; q < 32; ++q) {
      const unsigned hv = h16[q0 + q];
      pr = dot2(whhd[0][q], hv, pr);
      pz = dot2(whhd[1][q], hv, pz);
      pn = dot2(whhd[2][q], hv, pn);
    }
    pr = redu2(pr); pz = redu2(pz); pn = redu2(pn);

    if (ks == 0) {
      const float r = fast_sigmoid(gir + pr + bhr);
      const float z = fast_sigmoid(giz + pz + bhz);
      const float n = fast_tanh(gin + r * (pn + bhn));
      const float hg = (1.0f - z) * n + z * hreg;
      if (act) hreg = hg;                            // h_new = active ? hg : h
      h_lds[j] = hreg;                               // safe: GRU read h16, not h_lds
    }
    __syncthreads();                                 // (f) h_new visible

    // ---- LN + head contribution (inline) ----
    float s1 = 0.0f, s2 = 0.0f, sd = 0.0f;
    if (tid < Hh) {
      const float hv = h_lds[tid];
      s1 = hv; s2 = hv * hv; sd = hv * gw;
    }
    s1 = redu64(s1); s2 = redu64(s2); sd = redu64(sd);
    if (tid < Hh && lane == 0) {
      red_lds[wv * 3 + 0] = s1; red_lds[wv * 3 + 1] = s2; red_lds[wv * 3 + 2] = sd;
    }
    __syncthreads();                                 // (g) partials visible
    if (tid == 0 && m) {
      const float S1 = red_lds[0] + red_lds[3];
      const float S2 = red_lds[1] + red_lds[4];
      const float SD = red_lds[2] + red_lds[5];
      const float mu = S1 * (1.0f / 128.0f);
      const float var = S2 * (1.0f / 128.0f) - mu * mu;
      const float rstd = rsqrtf(var + 1e-5f);
      acc += rstd * (SD - mu * c1) + c0;
      cnt += 1.0f;
    }
  }

  if (tid == 0) out[b] = acc / fmaxf(cnt, 1.0f);     // FLOAT32 output
}

// ---------------- host ----------------
extern "C" void kernel_launch(void* const* d_in, const int* in_sizes, int n_in,
                              void* d_out, int out_size, void* d_ws, size_t ws_size,
                              hipStream_t stream) {
  const float* x    = (const float*)d_in[0];
  const float* dt   = (const float*)d_in[1];
  const int*   mask = (const int*)d_in[2];
  const float* Wx   = (const float*)d_in[3];
  const float* bx   = (const float*)d_in[4];
  const float* W1   = (const float*)d_in[5];
  const float* b1   = (const float*)d_in[6];
  const float* W2   = (const float*)d_in[7];
  const float* b2   = (const float*)d_in[8];
  const float* Wih  = (const float*)d_in[9];
  const float* bih  = (const float*)d_in[10];
  const float* Whh  = (const float*)d_in[11];
  const float* bhh  = (const float*)d_in[12];
  const float* lng  = (const float*)d_in[13];
  const float* lnb  = (const float*)d_in[14];
  const float* Wh   = (const float*)d_in[15];
  const float* bh   = (const float*)d_in[16];
  float* out = (float*)d_out;   // reference output dtype is float32

  k_fused<<<dim3(Bb), dim3(256), 0, stream>>>(
      x, dt, mask, Wx, bx, W1, b1, W2, b2, Wih, bih, Whh, bhh,
      lng, lnb, Wh, bh, out);
}

// Round 10
// 4632.653 us; speedup vs baseline: 5.3111x; 1.3305x over previous
//
#include <hip/hip_runtime.h>

#define Bb 256
#define Ll 1024
#define Ff 64
#define Ee 128
#define Hh 128

typedef _Float16 h2v __attribute__((ext_vector_type(2)));

__device__ __forceinline__ unsigned pack_h2(float a, float b) {
  h2v v; v[0] = (_Float16)a; v[1] = (_Float16)b;
  return __builtin_bit_cast(unsigned, v);
}
__device__ __forceinline__ float dot2(unsigned w, unsigned x, float acc) {
#if defined(__has_builtin) && __has_builtin(__builtin_amdgcn_fdot2)
  return __builtin_amdgcn_fdot2(__builtin_bit_cast(h2v, w),
                                __builtin_bit_cast(h2v, x), acc, false);
#else
  h2v wv = __builtin_bit_cast(h2v, w), xv = __builtin_bit_cast(h2v, x);
  acc = fmaf((float)wv[0], (float)xv[0], acc);
  return fmaf((float)wv[1], (float)xv[1], acc);
#endif
}
__device__ __forceinline__ float fast_tanh(float x) {
  float e = __expf(2.0f * x);
  return 1.0f - 2.0f / (e + 1.0f);
}
__device__ __forceinline__ float fast_sigmoid(float x) {
  return 1.0f / (1.0f + __expf(-x));
}
__device__ __forceinline__ float redu2(float v) { return v + __shfl_xor(v, 32); }

// One WG (256 thr, 4 waves) per batch row. Thread (j = wv*32+jl, ks = lane>>5)
// owns output row j with a 64-wide K-slice. All weights f16-pair dot2 except Wx.
// Wih lives in LDS (XOR-swizzled); W1/W2/Whh register-stationary.
__global__ __launch_bounds__(256, 1) void k_fused(
    const float* __restrict__ x, const float* __restrict__ dtp,
    const int* __restrict__ mask,
    const float* __restrict__ Wx, const float* __restrict__ bx,
    const float* __restrict__ W1, const float* __restrict__ b1,
    const float* __restrict__ W2, const float* __restrict__ b2,
    const float* __restrict__ Wih, const float* __restrict__ bih,
    const float* __restrict__ Whh, const float* __restrict__ bhh,
    const float* __restrict__ lng, const float* __restrict__ lnb,
    const float* __restrict__ Whd, const float* __restrict__ bhp,
    float* __restrict__ out)
{
  const int b = blockIdx.x;
  const int tid = threadIdx.x;
  const int lane = tid & 63;
  const int wv = tid >> 6;          // 0..3
  const int jl = lane & 31;
  const int ks = lane >> 5;         // 0..1
  const int j = (wv << 5) + jl;     // 0..127
  const int k0f = ks << 5;          // f32 slice base (F=64)
  const int q0 = ks << 5;           // 32 f16-pair slice base (K=128)

  __shared__ int act_lds[Ll];                        // 4 KB
  __shared__ __align__(16) unsigned wih_lds[3 * Hh * 64];  // 96 KB, swizzled
  __shared__ __align__(16) float x_lds[Ff];
  __shared__ __align__(16) unsigned xe16[Ee / 2];
  __shared__ __align__(16) unsigned u16[Hh / 2];
  __shared__ __align__(16) unsigned h16[2][Hh / 2];
  __shared__ float red_lds[12];

  // ---- act prepass: coalesced (lane-consecutive t) ----
  for (int c = wv; c < 16; c += 4) {
    const int t = (c << 6) + lane;
    int a = 0;
#pragma unroll 8
    for (int bb = 0; bb < Bb; ++bb) a |= mask[(size_t)bb * Ll + t];
    act_lds[t] = a;
  }

  // ---- Wih -> LDS as f16 pairs, XOR-swizzled within each 64-word row ----
  for (int idx = tid; idx < 3 * Hh * 64; idx += 256) {
    const int r = idx >> 6, w = idx & 63;
    const float wa = Wih[(size_t)r * Ee + 2 * w];
    const float wb = Wih[(size_t)r * Ee + 2 * w + 1];
    wih_lds[(r << 6) | (w ^ ((r & 15) << 2))] = pack_h2(wa, wb);
  }

  // ---- register-stationary weights ----
  float wx[32];
#pragma unroll
  for (int ii = 0; ii < 8; ++ii)
    *(float4*)&wx[4 * ii] = *(const float4*)&Wx[(size_t)j * Ff + k0f + 4 * ii];

  unsigned w1h[32], w2h[32], whr[32], whz[32], whn[32];
#pragma unroll
  for (int ii = 0; ii < 16; ++ii) {
    float4 a4;
    a4 = *(const float4*)&W1[(size_t)j * Hh + (q0 * 2) + 4 * ii];
    w1h[2 * ii] = pack_h2(a4.x, a4.y); w1h[2 * ii + 1] = pack_h2(a4.z, a4.w);
    a4 = *(const float4*)&W2[(size_t)j * Hh + (q0 * 2) + 4 * ii];
    w2h[2 * ii] = pack_h2(a4.x, a4.y); w2h[2 * ii + 1] = pack_h2(a4.z, a4.w);
    a4 = *(const float4*)&Whh[(size_t)j * Hh + (q0 * 2) + 4 * ii];
    whr[2 * ii] = pack_h2(a4.x, a4.y); whr[2 * ii + 1] = pack_h2(a4.z, a4.w);
    a4 = *(const float4*)&Whh[(size_t)(Hh + j) * Hh + (q0 * 2) + 4 * ii];
    whz[2 * ii] = pack_h2(a4.x, a4.y); whz[2 * ii + 1] = pack_h2(a4.z, a4.w);
    a4 = *(const float4*)&Whh[(size_t)(2 * Hh + j) * Hh + (q0 * 2) + 4 * ii];
    whn[2 * ii] = pack_h2(a4.x, a4.y); whn[2 * ii + 1] = pack_h2(a4.z, a4.w);
  }
  const float bxj = bx[j];
  const float b1j = b1[j], b2j = b2[j];
  const float bir = bih[j], biz = bih[Hh + j], bin_ = bih[2 * Hh + j];
  const float bhr = bhh[j], bhz = bhh[Hh + j], bhn = bhh[2 * Hh + j];
  const float gw = lng[j] * Whd[j];

  float c1 = 0.0f, c0 = 0.0f;
  for (int i = 0; i < Hh; ++i) { c1 += lng[i] * Whd[i]; c0 += lnb[i] * Whd[i]; }
  c0 += bhp[0];

  if (tid < Hh / 2) { h16[0][tid] = 0u; h16[1][tid] = 0u; }
  if (tid < 16)
    *(float4*)&x_lds[4 * tid] = *(const float4*)(x + ((size_t)b * Ll) * Ff + 4 * tid);
  float dtv = dtp[(size_t)b * Ll];
  int m = mask[(size_t)b * Ll];

  float hreg = 0.0f, gir = 0.0f, giz = 0.0f, gin = 0.0f;
  float acc = 0.0f, cnt = 0.0f;
  __syncthreads();

  int pp = 0;
#pragma unroll 1
  for (int t = 0; t < Ll; ++t) {
    // ---- prefetch t+1 (regs; stashed to LDS before barrier E) ----
    float4 xnext = {0, 0, 0, 0};
    float dtn = 0.0f; int mn = 0;
    const bool hn = (t + 1 < Ll);
    if (hn) {
      if (tid < 16) xnext = *(const float4*)(x + ((size_t)b * Ll + t + 1) * Ff + 4 * tid);
      dtn = dtp[(size_t)b * Ll + t + 1];
      mn = mask[(size_t)b * Ll + t + 1];
    }
    const int act = act_lds[t];
    const float stepv = dtv * (float)m * 0.25f;

    // ---- xe = relu(x @ Wx^T + bx) (f32, 4 accumulators) ----
    {
      float p0 = 0, p1 = 0, p2 = 0, p3 = 0;
#pragma unroll
      for (int c = 0; c < 8; ++c) {
        const float4 xv = *(const float4*)&x_lds[k0f + 4 * c];
        p0 = fmaf(wx[4 * c + 0], xv.x, p0); p1 = fmaf(wx[4 * c + 1], xv.y, p1);
        p2 = fmaf(wx[4 * c + 2], xv.z, p2); p3 = fmaf(wx[4 * c + 3], xv.w, p3);
      }
      float xev = redu2((p0 + p1) + (p2 + p3)) + bxj;
      xev = fmaxf(xev, 0.0f);
      const float xep = __shfl_xor(xev, 1);
      if (ks == 0 && (jl & 1) == 0) xe16[j >> 1] = pack_h2(xev, xep);
    }

    // ---- ODE substep 0, matvec1: u = tanh(W1 . h16[pp]) ----
    {
      const unsigned* hb = h16[pp];
      float a0 = 0, a1 = 0;
#pragma unroll
      for (int c = 0; c < 8; ++c) {
        const uint4 hv = *(const uint4*)&hb[q0 + 4 * c];
        a0 = dot2(w1h[4 * c + 0], hv.x, a0); a1 = dot2(w1h[4 * c + 1], hv.y, a1);
        a0 = dot2(w1h[4 * c + 2], hv.z, a0); a1 = dot2(w1h[4 * c + 3], hv.w, a1);
      }
      const float uu = fast_tanh(redu2(a0 + a1) + b1j);
      const float up = __shfl_xor(uu, 1);
      if (ks == 0 && (jl & 1) == 0) u16[j >> 1] = pack_h2(uu, up);
    }
    __syncthreads();                                   // C0: u16 + xe16 visible

    // ---- gi = xe @ W_ih^T + b_ih (LDS weights, 3 chains) ----
    {
      const int swi = (jl & 15) << 2;
      const unsigned* wr0 = &wih_lds[j << 6];
      const unsigned* wr1 = &wih_lds[(Hh + j) << 6];
      const unsigned* wr2 = &wih_lds[(2 * Hh + j) << 6];
      float gr = 0, gz = 0, gn = 0;
#pragma unroll
      for (int c = 0; c < 8; ++c) {
        const int off = (q0 + 4 * c) ^ swi;
        const uint4 xv = *(const uint4*)&xe16[q0 + 4 * c];
        const uint4 a0 = *(const uint4*)&wr0[off];
        gr = dot2(a0.x, xv.x, gr); gr = dot2(a0.y, xv.y, gr);
        gr = dot2(a0.z, xv.z, gr); gr = dot2(a0.w, xv.w, gr);
        const uint4 a1 = *(const uint4*)&wr1[off];
        gz = dot2(a1.x, xv.x, gz); gz = dot2(a1.y, xv.y, gz);
        gz = dot2(a1.z, xv.z, gz); gz = dot2(a1.w, xv.w, gz);
        const uint4 a2 = *(const uint4*)&wr2[off];
        gn = dot2(a2.x, xv.x, gn); gn = dot2(a2.y, xv.y, gn);
        gn = dot2(a2.z, xv.z, gn); gn = dot2(a2.w, xv.w, gn);
      }
      gir = redu2(gr) + bir; giz = redu2(gz) + biz; gin = redu2(gn) + bin_;
    }

    // ---- ODE substep 0, matvec2: h += stepv*(W2 . u + b2) -> h16[pp^1] ----
    {
      float a0 = 0, a1 = 0;
#pragma unroll
      for (int c = 0; c < 8; ++c) {
        const uint4 uv = *(const uint4*)&u16[q0 + 4 * c];
        a0 = dot2(w2h[4 * c + 0], uv.x, a0); a1 = dot2(w2h[4 * c + 1], uv.y, a1);
        a0 = dot2(w2h[4 * c + 2], uv.z, a0); a1 = dot2(w2h[4 * c + 3], uv.w, a1);
      }
      const float qq = redu2(a0 + a1) + b2j;
      hreg = fmaf(stepv, qq, hreg);
      const float hp = __shfl_xor(hreg, 1);
      if (ks == 0 && (jl & 1) == 0) h16[pp ^ 1][j >> 1] = pack_h2(hreg, hp);
    }
    __syncthreads();                                   // D0

    // ---- ODE substeps 1..3 ----
#pragma unroll
    for (int s = 1; s < 4; ++s) {
      const int rb = (pp + s) & 1;
      {
        const unsigned* hb = h16[rb];
        float a0 = 0, a1 = 0;
#pragma unroll
        for (int c = 0; c < 8; ++c) {
          const uint4 hv = *(const uint4*)&hb[q0 + 4 * c];
          a0 = dot2(w1h[4 * c + 0], hv.x, a0); a1 = dot2(w1h[4 * c + 1], hv.y, a1);
          a0 = dot2(w1h[4 * c + 2], hv.z, a0); a1 = dot2(w1h[4 * c + 3], hv.w, a1);
        }
        const float uu = fast_tanh(redu2(a0 + a1) + b1j);
        const float up = __shfl_xor(uu, 1);
        if (ks == 0 && (jl & 1) == 0) u16[j >> 1] = pack_h2(uu, up);
      }
      __syncthreads();                                 // C_s
      {
        float a0 = 0, a1 = 0;
#pragma unroll
        for (int c = 0; c < 8; ++c) {
          const uint4 uv = *(const uint4*)&u16[q0 + 4 * c];
          a0 = dot2(w2h[4 * c + 0], uv.x, a0); a1 = dot2(w2h[4 * c + 1], uv.y, a1);
          a0 = dot2(w2h[4 * c + 2], uv.z, a0); a1 = dot2(w2h[4 * c + 3], uv.w, a1);
        }
        const float qq = redu2(a0 + a1) + b2j;
        hreg = fmaf(stepv, qq, hreg);
        const float hp = __shfl_xor(hreg, 1);
        if (ks == 0 && (jl & 1) == 0) h16[rb ^ 1][j >> 1] = pack_h2(hreg, hp);
      }
      __syncthreads();                                 // D_s
    }
    // after 4 substeps h is back in h16[pp]

    // ---- GRU: gh = h @ W_hh^T (3 chains) ----
    {
      const unsigned* hb = h16[pp];
      float pr = 0, pz = 0, pn = 0;
#pragma unroll
      for (int c = 0; c < 8; ++c) {
        const uint4 hv = *(const uint4*)&hb[q0 + 4 * c];
        pr = dot2(whr[4 * c + 0], hv.x, pr); pr = dot2(whr[4 * c + 1], hv.y, pr);
        pr = dot2(whr[4 * c + 2], hv.z, pr); pr = dot2(whr[4 * c + 3], hv.w, pr);
        pz = dot2(whz[4 * c + 0], hv.x, pz); pz = dot2(whz[4 * c + 1], hv.y, pz);
        pz = dot2(whz[4 * c + 2], hv.z, pz); pz = dot2(whz[4 * c + 3], hv.w, pz);
        pn = dot2(whn[4 * c + 0], hv.x, pn); pn = dot2(whn[4 * c + 1], hv.y, pn);
        pn = dot2(whn[4 * c + 2], hv.z, pn); pn = dot2(whn[4 * c + 3], hv.w, pn);
      }
      pr = redu2(pr) + bhr; pz = redu2(pz) + bhz; pn = redu2(pn) + bhn;
      const float r = fast_sigmoid(gir + pr);
      const float z = fast_sigmoid(giz + pz);
      const float n = fast_tanh(gin + r * pn);
      const float hg = (1.0f - z) * n + z * hreg;
      if (act) hreg = hg;                              // uniform branch
      const float hp2 = __shfl_xor(hreg, 1);
      if (ks == 0 && (jl & 1) == 0) h16[pp ^ 1][j >> 1] = pack_h2(hreg, hp2);
    }

    // ---- LN partials (per-wave over its 32 owned h's, ks==0 lanes) ----
    {
      float s1 = hreg, s2 = hreg * hreg, sd = hreg * gw;
#pragma unroll
      for (int o = 1; o < 32; o <<= 1) {
        s1 += __shfl_xor(s1, o); s2 += __shfl_xor(s2, o); sd += __shfl_xor(sd, o);
      }
      if (ks == 0 && jl == 0) {
        red_lds[wv * 3 + 0] = s1; red_lds[wv * 3 + 1] = s2; red_lds[wv * 3 + 2] = sd;
      }
    }
    if (hn && tid < 16) *(float4*)&x_lds[4 * tid] = xnext;  // x_{t+1} stash
    __syncthreads();                                   // E: h16, red_lds, x_lds

    if (tid == 0 && m) {
      const float S1 = red_lds[0] + red_lds[3] + red_lds[6] + red_lds[9];
      const float S2 = red_lds[1] + red_lds[4] + red_lds[7] + red_lds[10];
      const float SD = red_lds[2] + red_lds[5] + red_lds[8] + red_lds[11];
      const float mu = S1 * (1.0f / 128.0f);
      const float var = S2 * (1.0f / 128.0f) - mu * mu;
      const float rstd = rsqrtf(var + 1e-5f);
      acc += rstd * (SD - mu * c1) + c0;
      cnt += 1.0f;
    }
    dtv = dtn; m = mn; pp ^= 1;
  }

  if (tid == 0) out[b] = acc / fmaxf(cnt, 1.0f);       // FLOAT32 output
}

// ---------------- host ----------------
extern "C" void kernel_launch(void* const* d_in, const int* in_sizes, int n_in,
                              void* d_out, int out_size, void* d_ws, size_t ws_size,
                              hipStream_t stream) {
  const float* x    = (const float*)d_in[0];
  const float* dt   = (const float*)d_in[1];
  const int*   mask = (const int*)d_in[2];
  const float* Wx   = (const float*)d_in[3];
  const float* bx   = (const float*)d_in[4];
  const float* W1   = (const float*)d_in[5];
  const float* b1   = (const float*)d_in[6];
  const float* W2   = (const float*)d_in[7];
  const float* b2   = (const float*)d_in[8];
  const float* Wih  = (const float*)d_in[9];
  const float* bih  = (const float*)d_in[10];
  const float* Whh  = (const float*)d_in[11];
  const float* bhh  = (const float*)d_in[12];
  const float* lng  = (const float*)d_in[13];
  const float* lnb  = (const float*)d_in[14];
  const float* Wh   = (const float*)d_in[15];
  const float* bh   = (const float*)d_in[16];
  float* out = (float*)d_out;

  k_fused<<<dim3(Bb), dim3(256), 0, stream>>>(
      x, dt, mask, Wx, bx, W1, b1, W2, b2, Wih, bih, Whh, bhh,
      lng, lnb, Wh, bh, out);
}

// Round 11
// 4083.649 us; speedup vs baseline: 6.0251x; 1.1344x over previous
//
#include <hip/hip_runtime.h>

#define Bb 256
#define Ll 1024
#define Ff 64
#define Ee 128
#define Hh 128
#define CH 32

typedef _Float16 h2v __attribute__((ext_vector_type(2)));

__device__ __forceinline__ unsigned pack_h2(float a, float b) {
  h2v v; v[0] = (_Float16)a; v[1] = (_Float16)b;
  return __builtin_bit_cast(unsigned, v);
}
__device__ __forceinline__ float dot2(unsigned w, unsigned x, float acc) {
#if defined(__has_builtin) && __has_builtin(__builtin_amdgcn_fdot2)
  return __builtin_amdgcn_fdot2(__builtin_bit_cast(h2v, w),
                                __builtin_bit_cast(h2v, x), acc, false);
#else
  h2v wv = __builtin_bit_cast(h2v, w), xv = __builtin_bit_cast(h2v, x);
  acc = fmaf((float)wv[0], (float)xv[0], acc);
  return fmaf((float)wv[1], (float)xv[1], acc);
#endif
}
// v + value_from(lane^1) via DPP quad_perm [1,0,3,2] — pure VALU, no LDS pipe
__device__ __forceinline__ float dppadd1(float v) {
  int s = __builtin_amdgcn_mov_dpp(__builtin_bit_cast(int, v), 0xB1, 0xF, 0xF, true);
  return v + __builtin_bit_cast(float, s);
}
__device__ __forceinline__ float fast_tanh(float x) {
  float e = __expf(2.0f * x);
  return 1.0f - 2.0f / (e + 1.0f);
}
__device__ __forceinline__ float fast_sigmoid(float x) {
  return 1.0f / (1.0f + __expf(-x));
}

// 64-wide K-slice matvec: 32 dot2, 2 chains, DPP reduce (sum valid on both pair lanes)
__device__ __forceinline__ float mv32(const unsigned* __restrict__ w,
                                      const unsigned* __restrict__ v, int q0) {
  float a0 = 0.0f, a1 = 0.0f;
#pragma unroll
  for (int c = 0; c < 8; ++c) {
    const uint4 hv = *(const uint4*)&v[q0 + 4 * c];
    a0 = dot2(w[4*c+0], hv.x, a0); a1 = dot2(w[4*c+1], hv.y, a1);
    a0 = dot2(w[4*c+2], hv.z, a0); a1 = dot2(w[4*c+3], hv.w, a1);
  }
  return dppadd1(a0 + a1);
}
// gi gate from LDS-resident (XOR-swizzled) Wih row
__device__ __forceinline__ float gi_gate(const unsigned* __restrict__ wrow,
                                         const unsigned* __restrict__ xe,
                                         int q0, int swi) {
  float g0 = 0.0f, g1 = 0.0f;
#pragma unroll
  for (int c = 0; c < 8; ++c) {
    const uint4 xv = *(const uint4*)&xe[q0 + 4 * c];
    const uint4 wv4 = *(const uint4*)&wrow[(q0 + 4 * c) ^ swi];
    g0 = dot2(wv4.x, xv.x, g0); g1 = dot2(wv4.y, xv.y, g1);
    g0 = dot2(wv4.z, xv.z, g0); g1 = dot2(wv4.w, xv.w, g1);
  }
  return dppadd1(g0 + g1);
}

// One WG (256 thr, 4 waves) per batch row. ks = lane&1 (K-half), j = wv*32 + (lane>>1).
__global__ __launch_bounds__(256, 1) void k_fused(
    const float* __restrict__ x, const float* __restrict__ dtp,
    const int* __restrict__ mask,
    const float* __restrict__ Wx, const float* __restrict__ bx,
    const float* __restrict__ W1, const float* __restrict__ b1,
    const float* __restrict__ W2, const float* __restrict__ b2,
    const float* __restrict__ Wih, const float* __restrict__ bih,
    const float* __restrict__ Whh, const float* __restrict__ bhh,
    const float* __restrict__ lng, const float* __restrict__ lnb,
    const float* __restrict__ Whd, const float* __restrict__ bhp,
    float* __restrict__ out)
{
  const int b = blockIdx.x;
  const int tid = threadIdx.x;
  const int lane = tid & 63;
  const int wv = tid >> 6;
  const int ks = lane & 1;
  const int jl = lane >> 1;            // 0..31
  const int j = (wv << 5) + jl;        // 0..127
  const int q0 = ks << 5;              // u32 base into 64-u32 (K=128) vectors
  const int q0x = ks << 4;             // u32 base into 32-u32 (F=64) x row
  const int swi = (j & 15) << 2;

  __shared__ int act_lds[Ll];                               // 4 KB
  __shared__ __align__(16) unsigned wih_lds[3 * Hh * 64];   // 96 KB, XOR-swizzled
  __shared__ __align__(16) unsigned x16[CH * 32];           // 4 KB, f16 pairs
  __shared__ __align__(16) unsigned xe16[Ee / 2];
  __shared__ __align__(16) unsigned u16[Hh / 2];
  __shared__ __align__(16) unsigned h16[2][Hh / 2];
  __shared__ float dt_ch[CH];
  __shared__ int   m_ch[CH];
  __shared__ float red_lds[24];

  // ---- act prepass (coalesced) ----
  for (int c = wv; c < 16; c += 4) {
    const int t = (c << 6) + lane;
    int a = 0;
#pragma unroll 8
    for (int bb = 0; bb < Bb; ++bb) a |= mask[(size_t)bb * Ll + t];
    act_lds[t] = a;
  }
  // ---- Wih -> LDS f16 pairs, XOR-swizzled within each 64-word row ----
  for (int idx = tid; idx < 3 * Hh * 64; idx += 256) {
    const int r = idx >> 6, w = idx & 63;
    wih_lds[(r << 6) | (w ^ ((r & 15) << 2))] =
        pack_h2(Wih[(size_t)r * Ee + 2 * w], Wih[(size_t)r * Ee + 2 * w + 1]);
  }
  // ---- register-stationary weights (f16 pairs) ----
  unsigned wxh[16];
#pragma unroll
  for (int ii = 0; ii < 8; ++ii) {
    const float4 a4 = *(const float4*)&Wx[(size_t)j * Ff + (ks << 5) + 4 * ii];
    wxh[2*ii] = pack_h2(a4.x, a4.y); wxh[2*ii+1] = pack_h2(a4.z, a4.w);
  }
  unsigned w1h[32], w2h[32], whr[32], whz[32], whn[32];
#pragma unroll
  for (int ii = 0; ii < 16; ++ii) {
    float4 a4;
    a4 = *(const float4*)&W1[(size_t)j * Hh + (ks << 6) + 4 * ii];
    w1h[2*ii] = pack_h2(a4.x, a4.y); w1h[2*ii+1] = pack_h2(a4.z, a4.w);
    a4 = *(const float4*)&W2[(size_t)j * Hh + (ks << 6) + 4 * ii];
    w2h[2*ii] = pack_h2(a4.x, a4.y); w2h[2*ii+1] = pack_h2(a4.z, a4.w);
    a4 = *(const float4*)&Whh[(size_t)j * Hh + (ks << 6) + 4 * ii];
    whr[2*ii] = pack_h2(a4.x, a4.y); whr[2*ii+1] = pack_h2(a4.z, a4.w);
    a4 = *(const float4*)&Whh[(size_t)(Hh + j) * Hh + (ks << 6) + 4 * ii];
    whz[2*ii] = pack_h2(a4.x, a4.y); whz[2*ii+1] = pack_h2(a4.z, a4.w);
    a4 = *(const float4*)&Whh[(size_t)(2 * Hh + j) * Hh + (ks << 6) + 4 * ii];
    whn[2*ii] = pack_h2(a4.x, a4.y); whn[2*ii+1] = pack_h2(a4.z, a4.w);
  }
  const float bxj = bx[j];
  const float b1j = b1[j], b2j = b2[j];
  const float bir = bih[j], biz = bih[Hh + j], bin_ = bih[2 * Hh + j];
  const float bhr = bhh[j], bhz = bhh[Hh + j], bhn = bhh[2 * Hh + j];
  const float gw = lng[j] * Whd[j];
  float c1 = 0.0f, c0 = 0.0f;
  for (int i = 0; i < Hh; ++i) { c1 += lng[i] * Whd[i]; c0 += lnb[i] * Whd[i]; }
  c0 += bhp[0];

  if (tid < Hh / 2) { h16[0][tid] = 0u; h16[1][tid] = 0u; }
  float hreg = 0.0f, gir = 0.0f, giz = 0.0f, gin = 0.0f;
  float acc = 0.0f, cnt = 0.0f;
  int pp = 0;
  __syncthreads();

#pragma unroll 1
  for (int t = 0; t < Ll; ++t) {
    const int tc = t & (CH - 1);
    if (tc == 0) {
      // ---- chunk refill: 32 steps of x (f16-packed) + dt + mask ----
      const int st = tid >> 3, g = tid & 7;
      const float* xp = x + ((size_t)b * Ll + t + st) * Ff + g * 8;
      const float4 a = *(const float4*)xp;
      const float4 c = *(const float4*)(xp + 4);
      uint4 pk;
      pk.x = pack_h2(a.x, a.y); pk.y = pack_h2(a.z, a.w);
      pk.z = pack_h2(c.x, c.y); pk.w = pack_h2(c.z, c.w);
      *(uint4*)&x16[st * 32 + g * 4] = pk;
      if (tid < CH) dt_ch[tid] = dtp[(size_t)b * Ll + t + tid];
      else if (tid < 2 * CH) m_ch[tid - CH] = mask[(size_t)b * Ll + t + (tid - CH)];
      __syncthreads();
    }
    const float dtv = dt_ch[tc];
    const int m = m_ch[tc];
    const int act = act_lds[t];
    const float stepv = dtv * (float)m * 0.25f;
    unsigned* hcur = h16[pp];

    // ---- phase A: xe + ODE substep0 matvec1 ----
    {
      float p0 = 0.0f, p1 = 0.0f;
      const unsigned* xr = &x16[tc * 32 + q0x];
#pragma unroll
      for (int c = 0; c < 4; ++c) {
        const uint4 xv = *(const uint4*)&xr[4 * c];
        p0 = dot2(wxh[4*c+0], xv.x, p0); p1 = dot2(wxh[4*c+1], xv.y, p1);
        p0 = dot2(wxh[4*c+2], xv.z, p0); p1 = dot2(wxh[4*c+3], xv.w, p1);
      }
      const float xev = fmaxf(dppadd1(p0 + p1) + bxj, 0.0f);
      if (ks == 0) ((_Float16*)xe16)[j] = (_Float16)xev;

      const float uu = fast_tanh(mv32(w1h, hcur, q0) + b1j);
      if (ks == 0) ((_Float16*)u16)[j] = (_Float16)uu;
    }
    __syncthreads();                         // C0

    // ---- phase B: ODE substep0 matvec2 + gi_r ----
    {
      hreg = fmaf(stepv, mv32(w2h, u16, q0) + b2j, hreg);
      if (ks == 0) ((_Float16*)hcur)[j] = (_Float16)hreg;
      gir = gi_gate(&wih_lds[j << 6], xe16, q0, swi) + bir;
    }
    __syncthreads();                         // D0

    // ---- substep1: matvec1 + gi_z ----
    {
      const float uu = fast_tanh(mv32(w1h, hcur, q0) + b1j);
      if (ks == 0) ((_Float16*)u16)[j] = (_Float16)uu;
      giz = gi_gate(&wih_lds[(Hh + j) << 6], xe16, q0, swi) + biz;
    }
    __syncthreads();                         // C1
    {
      hreg = fmaf(stepv, mv32(w2h, u16, q0) + b2j, hreg);
      if (ks == 0) ((_Float16*)hcur)[j] = (_Float16)hreg;
      gin = gi_gate(&wih_lds[(2 * Hh + j) << 6], xe16, q0, swi) + bin_;
    }
    __syncthreads();                         // D1

    // ---- substeps 2,3 ----
#pragma unroll
    for (int s = 2; s < 4; ++s) {
      {
        const float uu = fast_tanh(mv32(w1h, hcur, q0) + b1j);
        if (ks == 0) ((_Float16*)u16)[j] = (_Float16)uu;
      }
      __syncthreads();                       // C_s
      {
        hreg = fmaf(stepv, mv32(w2h, u16, q0) + b2j, hreg);
        if (ks == 0) ((_Float16*)hcur)[j] = (_Float16)hreg;
      }
      __syncthreads();                       // D_s
    }

    // ---- phase G: GRU + LN partials ----
    {
      float pr = 0.0f, pz = 0.0f, pn = 0.0f;
#pragma unroll
      for (int c = 0; c < 8; ++c) {
        const uint4 hv = *(const uint4*)&hcur[q0 + 4 * c];
        pr = dot2(whr[4*c+0], hv.x, pr); pr = dot2(whr[4*c+1], hv.y, pr);
        pr = dot2(whr[4*c+2], hv.z, pr); pr = dot2(whr[4*c+3], hv.w, pr);
        pz = dot2(whz[4*c+0], hv.x, pz); pz = dot2(whz[4*c+1], hv.y, pz);
        pz = dot2(whz[4*c+2], hv.z, pz); pz = dot2(whz[4*c+3], hv.w, pz);
        pn = dot2(whn[4*c+0], hv.x, pn); pn = dot2(whn[4*c+1], hv.y, pn);
        pn = dot2(whn[4*c+2], hv.z, pn); pn = dot2(whn[4*c+3], hv.w, pn);
      }
      pr = dppadd1(pr) + bhr; pz = dppadd1(pz) + bhz; pn = dppadd1(pn) + bhn;
      const float r = fast_sigmoid(gir + pr);
      const float z = fast_sigmoid(giz + pz);
      const float n = fast_tanh(gin + r * pn);
      const float hg = (1.0f - z) * n + z * hreg;
      if (act) hreg = hg;
      if (ks == 0) ((_Float16*)h16[pp ^ 1])[j] = (_Float16)hreg;

      // LN partials: xor levels 2,4,8,16 -> 16 distinct j per half-wave, each once
      float s1 = hreg, s2 = hreg * hreg, sd = hreg * gw;
#pragma unroll
      for (int o = 2; o <= 16; o <<= 1) {
        s1 += __shfl_xor(s1, o); s2 += __shfl_xor(s2, o); sd += __shfl_xor(sd, o);
      }
      if ((lane & 31) == 0) {
        const int slot = (wv << 1) | (lane >> 5);
        red_lds[slot * 3 + 0] = s1; red_lds[slot * 3 + 1] = s2; red_lds[slot * 3 + 2] = sd;
      }
    }
    __syncthreads();                         // E

    if (tid == 0 && m) {
      float S1 = 0.0f, S2 = 0.0f, SD = 0.0f;
#pragma unroll
      for (int q = 0; q < 8; ++q) {
        S1 += red_lds[q * 3 + 0]; S2 += red_lds[q * 3 + 1]; SD += red_lds[q * 3 + 2];
      }
      const float mu = S1 * (1.0f / 128.0f);
      const float var = S2 * (1.0f / 128.0f) - mu * mu;
      const float rstd = rsqrtf(var + 1e-5f);
      acc += rstd * (SD - mu * c1) + c0;
      cnt += 1.0f;
    }
    pp ^= 1;
  }

  if (tid == 0) out[b] = acc / fmaxf(cnt, 1.0f);   // FLOAT32 output
}

// ---------------- host ----------------
extern "C" void kernel_launch(void* const* d_in, const int* in_sizes, int n_in,
                              void* d_out, int out_size, void* d_ws, size_t ws_size,
                              hipStream_t stream) {
  const float* x    = (const float*)d_in[0];
  const float* dt   = (const float*)d_in[1];
  const int*   mask = (const int*)d_in[2];
  const float* Wx   = (const float*)d_in[3];
  const float* bx   = (const float*)d_in[4];
  const float* W1   = (const float*)d_in[5];
  const float* b1   = (const float*)d_in[6];
  const float* W2   = (const float*)d_in[7];
  const float* b2   = (const float*)d_in[8];
  const float* Wih  = (const float*)d_in[9];
  const float* bih  = (const float*)d_in[10];
  const float* Whh  = (const float*)d_in[11];
  const float* bhh  = (const float*)d_in[12];
  const float* lng  = (const float*)d_in[13];
  const float* lnb  = (const float*)d_in[14];
  const float* Wh   = (const float*)d_in[15];
  const float* bh   = (const float*)d_in[16];
  float* out = (float*)d_out;

  k_fused<<<dim3(Bb), dim3(256), 0, stream>>>(
      x, dt, mask, Wx, bx, W1, b1, W2, b2, Wih, bih, Whh, bhh,
      lng, lnb, Wh, bh, out);
}

// Round 12
// 3311.788 us; speedup vs baseline: 7.4293x; 1.2331x over previous
//
#include <hip/hip_runtime.h>

#define Bb 256
#define Ll 1024
#define Ff 64
#define Ee 128
#define Hh 128
#define CH 32

typedef _Float16 h2v __attribute__((ext_vector_type(2)));

__device__ __forceinline__ unsigned pack_h2(float a, float b) {
  h2v v; v[0] = (_Float16)a; v[1] = (_Float16)b;
  return __builtin_bit_cast(unsigned, v);
}
__device__ __forceinline__ float dot2(unsigned w, unsigned x, float acc) {
#if defined(__has_builtin) && __has_builtin(__builtin_amdgcn_fdot2)
  return __builtin_amdgcn_fdot2(__builtin_bit_cast(h2v, w),
                                __builtin_bit_cast(h2v, x), acc, false);
#else
  h2v wv = __builtin_bit_cast(h2v, w), xv = __builtin_bit_cast(h2v, x);
  acc = fmaf((float)wv[0], (float)xv[0], acc);
  return fmaf((float)wv[1], (float)xv[1], acc);
#endif
}
// + value from lane^1 (quad_perm [1,0,3,2]) — pure VALU
__device__ __forceinline__ float dppadd1(float v) {
  int s = __builtin_amdgcn_mov_dpp(__builtin_bit_cast(int, v), 0xB1, 0xF, 0xF, true);
  return v + __builtin_bit_cast(float, s);
}
// + value from lane^2 (quad_perm [2,3,0,1])
__device__ __forceinline__ float dppadd2(float v) {
  int s = __builtin_amdgcn_mov_dpp(__builtin_bit_cast(int, v), 0x4E, 0xF, 0xF, true);
  return v + __builtin_bit_cast(float, s);
}
__device__ __forceinline__ float qsum(float a0, float a1) {
  return dppadd2(dppadd1(a0 + a1));   // full sum across the 4-lane quad
}
__device__ __forceinline__ float fast_tanh(float x) {
  float e = __expf(2.0f * x);
  return 1.0f - 2.0f / (e + 1.0f);
}
__device__ __forceinline__ float fast_sigmoid(float x) {
  return 1.0f / (1.0f + __expf(-x));
}

// 32-wide K-slice matvec: 16 dot2, 2 chains, quad reduce
__device__ __forceinline__ float mv16(const unsigned* __restrict__ w,
                                      const unsigned* __restrict__ v, int q0) {
  float a0 = 0.0f, a1 = 0.0f;
#pragma unroll
  for (int c = 0; c < 4; ++c) {
    const uint4 hv = *(const uint4*)&v[q0 + 4 * c];
    a0 = dot2(w[4*c+0], hv.x, a0); a1 = dot2(w[4*c+1], hv.y, a1);
    a0 = dot2(w[4*c+2], hv.z, a0); a1 = dot2(w[4*c+3], hv.w, a1);
  }
  return qsum(a0, a1);
}
// gi gate from LDS-resident (XOR-swizzled) Wih row
__device__ __forceinline__ float gi_gate(const unsigned* __restrict__ wrow,
                                         const unsigned* __restrict__ xe,
                                         int q0, int swi) {
  float g0 = 0.0f, g1 = 0.0f;
#pragma unroll
  for (int c = 0; c < 4; ++c) {
    const uint4 xv = *(const uint4*)&xe[q0 + 4 * c];
    const uint4 w4 = *(const uint4*)&wrow[(q0 + 4 * c) ^ swi];
    g0 = dot2(w4.x, xv.x, g0); g1 = dot2(w4.y, xv.y, g1);
    g0 = dot2(w4.z, xv.z, g0); g1 = dot2(w4.w, xv.w, g1);
  }
  return qsum(g0, g1);
}

// One WG (512 thr, 8 waves = 2 waves/SIMD) per batch row.
// j = wv*16 + (lane>>2), ks = lane&3 (32-wide K-slice).
__global__ __launch_bounds__(512, 1) void k_fused(
    const float* __restrict__ x, const float* __restrict__ dtp,
    const int* __restrict__ mask,
    const float* __restrict__ Wx, const float* __restrict__ bx,
    const float* __restrict__ W1, const float* __restrict__ b1,
    const float* __restrict__ W2, const float* __restrict__ b2,
    const float* __restrict__ Wih, const float* __restrict__ bih,
    const float* __restrict__ Whh, const float* __restrict__ bhh,
    const float* __restrict__ lng, const float* __restrict__ lnb,
    const float* __restrict__ Whd, const float* __restrict__ bhp,
    float* __restrict__ out)
{
  const int b = blockIdx.x;
  const int tid = threadIdx.x;
  const int lane = tid & 63;
  const int wv = tid >> 6;            // 0..7
  const int jl = lane >> 2;           // 0..15
  const int ks = lane & 3;            // 0..3
  const int j = (wv << 4) + jl;       // 0..127
  const int q0 = ks << 4;             // u32 base in 64-u32 (K=128) arrays
  const int q0x = ks << 3;            // u32 base in 32-u32 (F=64) rows
  const int swi = (j & 15) << 2;
  const int swx = (j & 7) << 2;

  __shared__ int act_lds[Ll];                               // 4 KB
  __shared__ __align__(16) unsigned wih_lds[3 * Hh * 64];   // 96 KB, swizzled
  __shared__ __align__(16) unsigned wx_lds[Hh * 32];        // 16 KB, swizzled
  __shared__ __align__(16) unsigned x16[CH * 32];           // 4 KB
  __shared__ __align__(16) unsigned xe16[Ee / 2];
  __shared__ __align__(16) unsigned u16[Hh / 2];
  __shared__ __align__(16) unsigned h16[2][Hh / 2];
  __shared__ float bias_lds[6 * Hh];                        // bir,biz,bin,bhr,bhz,bhn
  __shared__ float dt_ch[CH];
  __shared__ int   m_ch[CH];
  __shared__ float red_lds[48];
  __shared__ float cc_lds[2];

  // ---- act prepass (lane-consecutive t: coalesced) ----
  for (int t0 = tid; t0 < Ll; t0 += 512) {
    int a = 0;
#pragma unroll 8
    for (int bb = 0; bb < Bb; ++bb) a |= mask[(size_t)bb * Ll + t0];
    act_lds[t0] = a;
  }
  // ---- Wih -> LDS f16 pairs, XOR-swizzled per 64-word row ----
  for (int idx = tid; idx < 3 * Hh * 64; idx += 512) {
    const int r = idx >> 6, w = idx & 63;
    wih_lds[(r << 6) | (w ^ ((r & 15) << 2))] =
        pack_h2(Wih[(size_t)r * Ee + 2 * w], Wih[(size_t)r * Ee + 2 * w + 1]);
  }
  // ---- Wx -> LDS f16 pairs, XOR-swizzled per 32-word row ----
  for (int idx = tid; idx < Hh * 32; idx += 512) {
    const int r = idx >> 5, w = idx & 31;
    wx_lds[(r << 5) | (w ^ ((r & 7) << 2))] =
        pack_h2(Wx[(size_t)r * Ff + 2 * w], Wx[(size_t)r * Ff + 2 * w + 1]);
  }
  // ---- per-j biases -> LDS ----
  for (int i = tid; i < 3 * Hh; i += 512) {
    bias_lds[i] = bih[i];             // bir | biz | bin
    bias_lds[3 * Hh + i] = bhh[i];    // bhr | bhz | bhn
  }
  if (tid == 0) {
    float s1 = 0.0f, s0 = 0.0f;
    for (int i = 0; i < Hh; ++i) { s1 += lng[i] * Whd[i]; s0 += lnb[i] * Whd[i]; }
    cc_lds[0] = s1; cc_lds[1] = s0 + bhp[0];
  }
  // ---- register-stationary weights (f16 pairs, 80 u32) ----
  unsigned w1h[16], w2h[16], whr[16], whz[16], whn[16];
#pragma unroll
  for (int ii = 0; ii < 8; ++ii) {
    float4 a4;
    a4 = *(const float4*)&W1[(size_t)j * Hh + (ks << 5) + 4 * ii];
    w1h[2*ii] = pack_h2(a4.x, a4.y); w1h[2*ii+1] = pack_h2(a4.z, a4.w);
    a4 = *(const float4*)&W2[(size_t)j * Hh + (ks << 5) + 4 * ii];
    w2h[2*ii] = pack_h2(a4.x, a4.y); w2h[2*ii+1] = pack_h2(a4.z, a4.w);
    a4 = *(const float4*)&Whh[(size_t)j * Hh + (ks << 5) + 4 * ii];
    whr[2*ii] = pack_h2(a4.x, a4.y); whr[2*ii+1] = pack_h2(a4.z, a4.w);
    a4 = *(const float4*)&Whh[(size_t)(Hh + j) * Hh + (ks << 5) + 4 * ii];
    whz[2*ii] = pack_h2(a4.x, a4.y); whz[2*ii+1] = pack_h2(a4.z, a4.w);
    a4 = *(const float4*)&Whh[(size_t)(2 * Hh + j) * Hh + (ks << 5) + 4 * ii];
    whn[2*ii] = pack_h2(a4.x, a4.y); whn[2*ii+1] = pack_h2(a4.z, a4.w);
  }
  const float bxj = bx[j];
  const float b1j = b1[j], b2j = b2[j];
  const float gw = lng[j] * Whd[j];

  if (tid < Hh / 2) { h16[0][tid] = 0u; h16[1][tid] = 0u; }
  float hreg = 0.0f, gir = 0.0f, giz = 0.0f, gin = 0.0f;
  float acc = 0.0f, cnt = 0.0f;
  int pp = 0;
  __syncthreads();

#pragma unroll 1
  for (int t = 0; t < Ll; ++t) {
    const int tc = t & (CH - 1);
    if (tc == 0) {
      // ---- chunk refill: 32 steps of x (f16-packed) + dt + mask ----
      const int st = tid >> 4, g = tid & 15;
      const float4 a = *(const float4*)(x + ((size_t)b * Ll + t + st) * Ff + g * 4);
      uint2 pk; pk.x = pack_h2(a.x, a.y); pk.y = pack_h2(a.z, a.w);
      *(uint2*)&x16[st * 32 + g * 2] = pk;
      if (tid < CH) dt_ch[tid] = dtp[(size_t)b * Ll + t + tid];
      else if (tid < 2 * CH) m_ch[tid - CH] = mask[(size_t)b * Ll + t + (tid - CH)];
      __syncthreads();
    }
    const float dtv = dt_ch[tc];
    const int m = m_ch[tc];
    const int act = act_lds[t];
    const float stepv = dtv * (float)m * 0.25f;
    unsigned* hcur = h16[pp];

    // ---- phase A: xe + ODE substep0 matvec1 ----
    {
      float p0 = 0.0f, p1 = 0.0f;
      const unsigned* xr = &x16[tc * 32];
      const unsigned* wxr = &wx_lds[j << 5];
#pragma unroll
      for (int c = 0; c < 2; ++c) {
        const uint4 xv = *(const uint4*)&xr[q0x + 4 * c];
        const uint4 w4 = *(const uint4*)&wxr[(q0x + 4 * c) ^ swx];
        p0 = dot2(w4.x, xv.x, p0); p1 = dot2(w4.y, xv.y, p1);
        p0 = dot2(w4.z, xv.z, p0); p1 = dot2(w4.w, xv.w, p1);
      }
      const float xev = fmaxf(qsum(p0, p1) + bxj, 0.0f);
      if (ks == 0) ((_Float16*)xe16)[j] = (_Float16)xev;

      const float uu = fast_tanh(mv16(w1h, hcur, q0) + b1j);
      if (ks == 0) ((_Float16*)u16)[j] = (_Float16)uu;
    }
    __syncthreads();                         // C0

    // ---- phase B: substep0 matvec2 + gi_r ----
    {
      hreg = fmaf(stepv, mv16(w2h, u16, q0) + b2j, hreg);
      if (ks == 0) ((_Float16*)hcur)[j] = (_Float16)hreg;
      gir = gi_gate(&wih_lds[j << 6], xe16, q0, swi) + bias_lds[j];
    }
    __syncthreads();                         // D0

    // ---- substep1 + gi_z / gi_n ----
    {
      const float uu = fast_tanh(mv16(w1h, hcur, q0) + b1j);
      if (ks == 0) ((_Float16*)u16)[j] = (_Float16)uu;
      giz = gi_gate(&wih_lds[(Hh + j) << 6], xe16, q0, swi) + bias_lds[Hh + j];
    }
    __syncthreads();                         // C1
    {
      hreg = fmaf(stepv, mv16(w2h, u16, q0) + b2j, hreg);
      if (ks == 0) ((_Float16*)hcur)[j] = (_Float16)hreg;
      gin = gi_gate(&wih_lds[(2 * Hh + j) << 6], xe16, q0, swi) + bias_lds[2 * Hh + j];
    }
    __syncthreads();                         // D1

    // ---- substeps 2,3 ----
#pragma unroll
    for (int s = 2; s < 4; ++s) {
      {
        const float uu = fast_tanh(mv16(w1h, hcur, q0) + b1j);
        if (ks == 0) ((_Float16*)u16)[j] = (_Float16)uu;
      }
      __syncthreads();                       // C_s
      {
        hreg = fmaf(stepv, mv16(w2h, u16, q0) + b2j, hreg);
        if (ks == 0) ((_Float16*)hcur)[j] = (_Float16)hreg;
      }
      __syncthreads();                       // D_s
    }

    // ---- phase G: GRU + LN partials ----
    {
      float pr = 0.0f, pz = 0.0f, pn = 0.0f;
#pragma unroll
      for (int c = 0; c < 4; ++c) {
        const uint4 hv = *(const uint4*)&hcur[q0 + 4 * c];
        pr = dot2(whr[4*c+0], hv.x, pr); pr = dot2(whr[4*c+1], hv.y, pr);
        pr = dot2(whr[4*c+2], hv.z, pr); pr = dot2(whr[4*c+3], hv.w, pr);
        pz = dot2(whz[4*c+0], hv.x, pz); pz = dot2(whz[4*c+1], hv.y, pz);
        pz = dot2(whz[4*c+2], hv.z, pz); pz = dot2(whz[4*c+3], hv.w, pz);
        pn = dot2(whn[4*c+0], hv.x, pn); pn = dot2(whn[4*c+1], hv.y, pn);
        pn = dot2(whn[4*c+2], hv.z, pn); pn = dot2(whn[4*c+3], hv.w, pn);
      }
      pr = qsum(pr, 0.0f) + bias_lds[3 * Hh + j];
      pz = qsum(pz, 0.0f) + bias_lds[4 * Hh + j];
      pn = qsum(pn, 0.0f) + bias_lds[5 * Hh + j];
      const float r = fast_sigmoid(gir + pr);
      const float z = fast_sigmoid(giz + pz);
      const float n = fast_tanh(gin + r * pn);
      const float hg = (1.0f - z) * n + z * hreg;
      if (act) hreg = hg;
      if (ks == 0) ((_Float16*)h16[pp ^ 1])[j] = (_Float16)hreg;

      // LN partials: xor 4,8,16 sums 8 distinct j per half-wave
      float s1 = hreg, s2 = hreg * hreg, sd = hreg * gw;
#pragma unroll
      for (int o = 4; o <= 16; o <<= 1) {
        s1 += __shfl_xor(s1, o); s2 += __shfl_xor(s2, o); sd += __shfl_xor(sd, o);
      }
      if ((lane & 31) == 0) {
        const int slot = (wv << 1) | (lane >> 5);
        red_lds[slot * 3 + 0] = s1; red_lds[slot * 3 + 1] = s2; red_lds[slot * 3 + 2] = sd;
      }
    }
    __syncthreads();                         // E

    if (tid == 0 && m) {
      float S1 = 0.0f, S2 = 0.0f, SD = 0.0f;
#pragma unroll
      for (int q = 0; q < 16; ++q) {
        S1 += red_lds[q * 3 + 0]; S2 += red_lds[q * 3 + 1]; SD += red_lds[q * 3 + 2];
      }
      const float mu = S1 * (1.0f / 128.0f);
      const float var = S2 * (1.0f / 128.0f) - mu * mu;
      const float rstd = rsqrtf(var + 1e-5f);
      acc += rstd * (SD - mu * cc_lds[0]) + cc_lds[1];
      cnt += 1.0f;
    }
    pp ^= 1;
  }

  if (tid == 0) out[b] = acc / fmaxf(cnt, 1.0f);   // FLOAT32 output
}

// ---------------- host ----------------
extern "C" void kernel_launch(void* const* d_in, const int* in_sizes, int n_in,
                              void* d_out, int out_size, void* d_ws, size_t ws_size,
                              hipStream_t stream) {
  const float* x    = (const float*)d_in[0];
  const float* dt   = (const float*)d_in[1];
  const int*   mask = (const int*)d_in[2];
  const float* Wx   = (const float*)d_in[3];
  const float* bx   = (const float*)d_in[4];
  const float* W1   = (const float*)d_in[5];
  const float* b1   = (const float*)d_in[6];
  const float* W2   = (const float*)d_in[7];
  const float* b2   = (const float*)d_in[8];
  const float* Wih  = (const float*)d_in[9];
  const float* bih  = (const float*)d_in[10];
  const float* Whh  = (const float*)d_in[11];
  const float* bhh  = (const float*)d_in[12];
  const float* lng  = (const float*)d_in[13];
  const float* lnb  = (const float*)d_in[14];
  const float* Wh   = (const float*)d_in[15];
  const float* bh   = (const float*)d_in[16];
  float* out = (float*)d_out;

  k_fused<<<dim3(Bb), dim3(512), 0, stream>>>(
      x, dt, mask, Wx, bx, W1, b1, W2, b2, Wih, bih, Whh, bhh,
      lng, lnb, Wh, bh, out);
}